// Round 2
// 166.676 us; speedup vs baseline: 1.7640x; 1.7640x over previous
//
#include <hip/hip_runtime.h>

typedef unsigned int u32;
typedef unsigned short u16;
typedef _Float16 h2 __attribute__((ext_vector_type(2)));
typedef _Float16 h4 __attribute__((ext_vector_type(4)));
typedef float f4 __attribute__((ext_vector_type(4)));

#define B_ 64
#define N_ 8192
#define DI 8
#define O_ 10
#define DO_ 16
#define OD 160          // O_*DO_
#define NCHUNK 32       // n per block; grid = 256 blocks = 1/CU
#define NPART 256       // partial buffers (= grid) -- ws >= 5.3 MB proven R5-R10
#define CHN 4           // n per LDS chunk (double-buffered: 8 chunks)
#define NCHK (NCHUNK / CHN)
#define WROW (OD * DI)  // 1280 elems per n
#define CHH (CHN * WROW)// 5120 f16 per chunk buffer
#define CSTR 164        // eta-combine row stride (floats): 164%32=4 -> <=2-way banks

// cvt_pkrtz returns __fp16-vec2; bit_cast to our _Float16-vec2 (same bits).
static __device__ __forceinline__ h2 pkrtz(float a, float b) {
    return __builtin_bit_cast(h2, __builtin_amdgcn_cvt_pkrtz(a, b));
}

// R13 = R12 with the cvt_pkrtz type fix. MFMA rewrite: u_hat = W.x on matrix
// cores (f32_16x16x16_f16, K=8 of 16 used, zero-padded upper-K lanes).
// Waves = (b-tile tau = w&3 [16 b], n-half eta = w>>2). C-frag: col = lane&15
// = b-in-tile, rows = 4*(lane>>4)+j = d. A-frag: lane row = lane&15 = d,
// k = 4*(lane>>4)+j = i (lanes hh>=2 carry zeros). B-frag: col = lane&15 = b,
// k = i, from x via global float4 -> cvt_pkrtz. W staged once into LDS as f16
// (linear copy+convert, coalesced; A-reads <=2-way bank-aliased = free per
// m136). PHASE 0 accumulates straight through the MFMA C operand. PHASE 1
// routing: agreement = 4 FMA + packed-f16 cross-sum over the 4 hh-lane-groups
// (ds_swizzle ^16 + ds_bpermute ^32 + v_pk_add_f16, 2 DS ops per o-pair),
// softmax in-lane (replicated x4), weighted accumulate 4 FMA/o. eta-pairs
// combined via one LDS round-trip at the end (stage buffer is dead by then).
template <int PHASE, int TAIL>
__global__ __launch_bounds__(512, 2)
void caps_pass(const float* __restrict__ Xf, const float* __restrict__ Wf,
               const u16* __restrict__ Vb, float* __restrict__ Sout,
               _Float16* __restrict__ Sh) {
    __shared__ float smem[B_ * CSTR];        // 41984 B; first 20480 B = W stage
    _Float16* stage = (_Float16*)smem;

    const int tid  = threadIdx.x;
    const int lane = tid & 63;
    const int c    = lane & 15;              // b-in-tile / A-row
    const int hh   = lane >> 4;              // k-group 0..3 (>=2: zero K half)
    const int w    = __builtin_amdgcn_readfirstlane(tid >> 6);
    const int tau  = w & 3, eta = w >> 2;
    const int b    = tau * 16 + c;
    const int nb   = blockIdx.x * NCHUNK;

    const int a32  = (lane ^ 32) << 2;       // ds_bpermute byte index

    // staging map: 2560 float2 per chunk / 512 threads = 5 each; dst layout is
    // byte-order-identical to global (linear f16 copy) -> trivially coalesced.
    int off[5];
    #pragma unroll
    for (int k = 0; k < 5; ++k) off[k] = (tid + k * 512) * 2;

    float2 st[5];
    {   // prologue: chunk 0 -> buf 0
        const float* src = Wf + (size_t)nb * WROW;
        #pragma unroll
        for (int k = 0; k < 5; ++k) st[k] = *(const float2*)(src + off[k]);
        #pragma unroll
        for (int k = 0; k < 5; ++k)
            *(h2*)&stage[off[k]] = pkrtz(st[k].x, st[k].y);
    }

    // v for this lane's b: v[b][o][4*hh + j], f16 feedback (upgraded from bf16)
    f4 vv[O_];
    if (PHASE > 0) {
        const _Float16* vp = (const _Float16*)Vb + (size_t)b * OD + 4 * hh;
        #pragma unroll
        for (int oo = 0; oo < O_; ++oo) {
            const h4 hv = *(const h4*)(vp + oo * DO_);
            vv[oo][0] = (float)hv[0]; vv[oo][1] = (float)hv[1];
            vv[oo][2] = (float)hv[2]; vv[oo][3] = (float)hv[3];
        }
    }

    const f4 fz = {0.f, 0.f, 0.f, 0.f};
    f4 acc[O_];
    #pragma unroll
    for (int oo = 0; oo < O_; ++oo) acc[oo] = fz;

    // x pipeline (1 n ahead): lane reads x[b][n][4*hh .. 4*hh+3] (hh>=2: dummy
    // in-bounds read at offset 0; frag forced zero anyway).
    const int ioff = (hh < 2) ? 4 * hh : 0;
    const float* xb = Xf + ((size_t)b * N_ + nb + eta * 2) * DI + ioff;
    float4 xcur = *(const float4*)xb;

    __syncthreads();

    #pragma unroll 1
    for (int ch = 0; ch < NCHK; ++ch) {
        if (ch < NCHK - 1) {   // issue next chunk's global loads (overlap)
            const float* src = Wf + (size_t)(nb + (ch + 1) * CHN) * WROW;
            #pragma unroll
            for (int k = 0; k < 5; ++k) st[k] = *(const float2*)(src + off[k]);
        }
        const _Float16* wb = stage + (ch & 1) * CHH;

        #pragma unroll
        for (int kk = 0; kk < 2; ++kk) {
            const int s = ch * 2 + kk;       // this wave's n-seq index 0..15
            float4 xnext = xcur;
            if (s < 15) {
                const int s1 = s + 1;
                xnext = *(const float4*)(xb + ((s1 >> 1) * CHN + (s1 & 1)) * DI);
            }

            h4 bf = {(_Float16)0.f, (_Float16)0.f, (_Float16)0.f, (_Float16)0.f};
            if (hh < 2) {
                const h2 lo = pkrtz(xcur.x, xcur.y);
                const h2 hi = pkrtz(xcur.z, xcur.w);
                bf[0] = lo[0]; bf[1] = lo[1]; bf[2] = hi[0]; bf[3] = hi[1];
            }
            xcur = xnext;

            // A rows from LDS: lane reads W[n][o][d = lane&15][i = 4*hh..+3]
            const _Float16* wr = wb + (eta * 2 + kk) * WROW + c * DI + ioff;
            f4 u[O_];
            #pragma unroll
            for (int oo = 0; oo < O_; ++oo) {
                h4 af = {(_Float16)0.f, (_Float16)0.f, (_Float16)0.f, (_Float16)0.f};
                if (hh < 2) af = *(const h4*)(wr + oo * (DO_ * DI));
                if (PHASE == 0) {   // c_ij = 0.1 uniform: chain C through MFMA
                    acc[oo] = __builtin_amdgcn_mfma_f32_16x16x16f16(af, bf, acc[oo], 0, 0, 0);
                } else {
                    u[oo] = __builtin_amdgcn_mfma_f32_16x16x16f16(af, bf, fz, 0, 0, 0);
                }
            }

            if (PHASE > 0) {
                float tex[O_];
                #pragma unroll
                for (int q = 0; q < 5; ++q) {
                    const int o0 = 2 * q, o1 = 2 * q + 1;
                    const float p0 = u[o0][0]*vv[o0][0] + u[o0][1]*vv[o0][1]
                                   + u[o0][2]*vv[o0][2] + u[o0][3]*vv[o0][3];
                    const float p1 = u[o1][0]*vv[o1][0] + u[o1][1]*vv[o1][1]
                                   + u[o1][2]*vv[o1][2] + u[o1][3]*vv[o1][3];
                    h2 pk = pkrtz(p0, p1);
                    int pi = __builtin_bit_cast(int, pk);
                    pk = pk + __builtin_bit_cast(h2, __builtin_amdgcn_ds_swizzle(pi, 0x401F));
                    pi = __builtin_bit_cast(int, pk);
                    pk = pk + __builtin_bit_cast(h2, __builtin_amdgcn_ds_bpermute(a32, pi));
                    tex[o0] = __expf((float)pk[0]);
                    tex[o1] = __expf((float)pk[1]);
                }
                const float den = (((tex[0] + tex[1]) + (tex[2] + tex[3]))
                                 + ((tex[4] + tex[5]) + (tex[6] + tex[7])))
                                 + (tex[8] + tex[9]);
                const float rinv = 1.0f / den;
                #pragma unroll
                for (int oo = 0; oo < O_; ++oo) {
                    const float co = tex[oo] * rinv;
                    acc[oo][0] = fmaf(co, u[oo][0], acc[oo][0]);
                    acc[oo][1] = fmaf(co, u[oo][1], acc[oo][1]);
                    acc[oo][2] = fmaf(co, u[oo][2], acc[oo][2]);
                    acc[oo][3] = fmaf(co, u[oo][3], acc[oo][3]);
                }
            }
        }

        if (ch < NCHK - 1) {   // write next chunk into the buffer just consumed
            _Float16* dst = stage + ((ch + 1) & 1) * CHH;
            #pragma unroll
            for (int k = 0; k < 5; ++k)
                *(h2*)&dst[off[k]] = pkrtz(st[k].x, st[k].y);
        }
        __syncthreads();
    }

    // eta-combine: eta=1 waves park their partial in LDS (stage is dead now)
    if (eta == 1) {
        #pragma unroll
        for (int oo = 0; oo < O_; ++oo)
            *(f4*)&smem[b * CSTR + oo * DO_ + 4 * hh] = acc[oo];
    }
    __syncthreads();
    if (eta == 0) {
        #pragma unroll
        for (int oo = 0; oo < O_; ++oo)
            acc[oo] = acc[oo] + *(const f4*)&smem[b * CSTR + oo * DO_ + 4 * hh];
        const float sc = (PHASE == 0) ? 0.1f : 1.0f;
        if (TAIL == 1) {   // each (b, od) owned by exactly one lane
            _Float16* my = Sh + (size_t)blockIdx.x * (B_ * OD) + (size_t)b * OD;
            #pragma unroll
            for (int oo = 0; oo < O_; ++oo) {
                h4 hq;
                hq[0] = (_Float16)(sc * acc[oo][0]);
                hq[1] = (_Float16)(sc * acc[oo][1]);
                hq[2] = (_Float16)(sc * acc[oo][2]);
                hq[3] = (_Float16)(sc * acc[oo][3]);
                *(h4*)(my + oo * DO_ + 4 * hh) = hq;
            }
        } else {
            float* Sg = Sout + (size_t)b * OD;
            #pragma unroll
            for (int oo = 0; oo < O_; ++oo) {
                atomicAdd(&Sg[oo * DO_ + 4 * hh + 0], sc * acc[oo][0]);
                atomicAdd(&Sg[oo * DO_ + 4 * hh + 1], sc * acc[oo][1]);
                atomicAdd(&Sg[oo * DO_ + 4 * hh + 2], sc * acc[oo][2]);
                atomicAdd(&Sg[oo * DO_ + 4 * hh + 3], sc * acc[oo][3]);
            }
        }
    }
}

// Fused cross-block reduce + squash (norm over OUT-CAPSULE axis, per (b,d)).
// R12: partial-reduce parallelized 6-wide per od (was 1 thread x 256 serial
// loads -> latency-bound ~28us each). PHASE 0: V0f=v0 fp32, Vb=f16(v0).
// PHASE 1: Vb=f16(v0+v1). PHASE 2: out fp32.
template <int PHASE>
__global__ __launch_bounds__(1024)
void caps_reduce_fin(const _Float16* __restrict__ Sp, int nparts,
                     float* __restrict__ V0f, u16* __restrict__ Vb,
                     float* __restrict__ out) {
    __shared__ float sg[6 * OD];
    __shared__ float s_s[OD];
    __shared__ float s_scale[DO_];
    const int b = blockIdx.x;
    const int t = threadIdx.x;
    if (t < 6 * OD) {
        const int g = t / OD, od = t - g * OD;
        float acc = 0.0f;
        const _Float16* p0 = Sp + (size_t)b * OD + od;
        #pragma unroll 4
        for (int p = g; p < nparts; p += 6)
            acc += (float)p0[(size_t)p * (B_ * OD)];
        sg[t] = acc;
    }
    __syncthreads();
    if (t < OD) {
        float s = 0.0f;
        #pragma unroll
        for (int gg = 0; gg < 6; ++gg) s += sg[gg * OD + t];
        s_s[t] = s;
    }
    __syncthreads();
    if (t < DO_) {
        float norm = 0.0f;
        #pragma unroll
        for (int o = 0; o < O_; ++o) { float x = s_s[o * DO_ + t]; norm = fmaf(x, x, norm); }
        s_scale[t] = norm / (1.0f + norm) * rsqrtf(norm + 1e-9f);
    }
    __syncthreads();
    if (t < OD) {
        const float v = s_s[t] * s_scale[t & 15];
        const int idx = b * OD + t;
        if (PHASE == 0) {
            V0f[idx] = v;
            _Float16 h = (_Float16)v;
            Vb[idx] = __builtin_bit_cast(u16, h);
        } else if (PHASE == 1) {
            const float vs = V0f[idx] + v;
            _Float16 h = (_Float16)vs;
            Vb[idx] = __builtin_bit_cast(u16, h);
        } else {
            out[idx] = v;
        }
    }
}

// Finalize for the atomic fallback (also zeroes S for the next pass).
template <int PHASE>
__global__ __launch_bounds__(1024)
void caps_finalize(float* __restrict__ S, float* __restrict__ V0f,
                   u16* __restrict__ Vb, float* __restrict__ out) {
    const int tid = threadIdx.x;      // 1024 = 64 b * 16 d
    const int b = tid >> 4, d = tid & 15;
    float sv[O_];
    float norm = 0.0f;
    #pragma unroll
    for (int o = 0; o < O_; ++o) {
        sv[o] = S[b * OD + o * DO_ + d];
        norm = fmaf(sv[o], sv[o], norm);
    }
    const float scale = norm / (1.0f + norm) * rsqrtf(norm + 1e-9f);
    #pragma unroll
    for (int o = 0; o < O_; ++o) {
        const int idx = b * OD + o * DO_ + d;
        const float v = scale * sv[o];
        if (PHASE == 0) {
            V0f[idx] = v;
            _Float16 hcv = (_Float16)v;
            Vb[idx] = __builtin_bit_cast(u16, hcv);
            S[idx] = 0.0f;
        } else if (PHASE == 1) {
            const float vs = V0f[idx] + v;
            _Float16 hcv = (_Float16)vs;
            Vb[idx] = __builtin_bit_cast(u16, hcv);
            S[idx] = 0.0f;
        } else {
            out[idx] = v;
        }
    }
}

extern "C" void kernel_launch(void* const* d_in, const int* in_sizes, int n_in,
                              void* d_out, int out_size, void* d_ws, size_t ws_size,
                              hipStream_t stream) {
    const float* Xf = (const float*)d_in[0];   // x: [64, 8192, 8] fp32
    const float* Wf = (const float*)d_in[1];   // W: [1, 8192, 10, 16, 8] fp32
    float* out = (float*)d_out;

    const size_t velems = (size_t)B_ * OD;                   // 10240
    const size_t base = velems * 4 + velems * 2;             // V0f fp32 + Vb f16
    const size_t need = base + (size_t)NPART * velems * 2;   // 5,304,320 B (proven fits)

    float* V0f = (float*)d_ws;
    u16* Vb = (u16*)(V0f + velems);
    const dim3 grid(N_ / NCHUNK), blk(512), rgrid(B_), rblk(1024);

    if (ws_size >= need) {
        // fast path: fp16 per-block partials (proven)
        _Float16* P = (_Float16*)((char*)d_ws + base);
        caps_pass<0, 1><<<grid, blk, 0, stream>>>(Xf, Wf, nullptr, nullptr, P);
        caps_reduce_fin<0><<<rgrid, rblk, 0, stream>>>(P, NPART, V0f, Vb, nullptr);
        caps_pass<1, 1><<<grid, blk, 0, stream>>>(Xf, Wf, Vb, nullptr, P);
        caps_reduce_fin<1><<<rgrid, rblk, 0, stream>>>(P, NPART, V0f, Vb, nullptr);
        caps_pass<1, 1><<<grid, blk, 0, stream>>>(Xf, Wf, Vb, nullptr, P);
        caps_reduce_fin<2><<<rgrid, rblk, 0, stream>>>(P, NPART, nullptr, nullptr, out);
    } else {
        // fallback: global atomic accumulator
        float* S = (float*)((char*)d_ws + base);
        const dim3 one(1), fblk(1024);
        (void)hipMemsetAsync(S, 0, velems * sizeof(float), stream);
        caps_pass<0, 2><<<grid, blk, 0, stream>>>(Xf, Wf, nullptr, S, nullptr);
        caps_finalize<0><<<one, fblk, 0, stream>>>(S, V0f, Vb, nullptr);
        caps_pass<1, 2><<<grid, blk, 0, stream>>>(Xf, Wf, Vb, S, nullptr);
        caps_finalize<1><<<one, fblk, 0, stream>>>(S, V0f, Vb, nullptr);
        caps_pass<1, 2><<<grid, blk, 0, stream>>>(Xf, Wf, Vb, S, nullptr);
        caps_finalize<2><<<one, fblk, 0, stream>>>(S, nullptr, nullptr, out);
    }
}